// Round 10
// baseline (42.088 us; speedup 1.0000x reference)
//
#include <hip/hip_runtime.h>
#include <math.h>

#define NB 4
#define WDIM 128
#define KDIM 256
#define EDIM 256

__device__ __forceinline__ float dot4(float4 a, float4 b) {
    return a.x * b.x + a.y * b.y + a.z * b.z + a.w * b.w;
}

// ---------------- k_ut10: dual GEMM u,t + t-transpose (r8 verified, unchanged) ----------------
// grid 512: blk = b*128 + kt*4 + eq. Block = 8 k x 64 e.
// u_ws[b][k][e] = sum_w v*W1;  tT_ws[b][e][k] = sum_w v*W2 + lin_b[e]
__global__ __launch_bounds__(256) void k_ut10(const float* __restrict__ x,
                                              const float* __restrict__ lin_w,
                                              const float* __restrict__ lin_b,
                                              float* __restrict__ u_ws,
                                              float* __restrict__ tT_ws) {
    __shared__ float vrow[8 * WDIM];   // [k 8][w 128]
    __shared__ float t_lds[64][9];     // [e 64][k 8] padded
    const int blk = blockIdx.x;
    const int b  = blk >> 7;
    const int kt = (blk >> 2) & 31;
    const int eq = blk & 3;
    const int k0 = kt * 8;
    const int tid = threadIdx.x;
    const int el  = tid & 63;
    const int e   = eq * 64 + el;
    const int ks  = tid >> 6;

    if (tid < WDIM) {
        const float* xp = x + ((size_t)b * WDIM + tid) * KDIM + k0;
        float4 v0 = *(const float4*)xp;
        float4 v1 = *(const float4*)(xp + 4);
        vrow[0 * WDIM + tid] = v0.x; vrow[1 * WDIM + tid] = v0.y;
        vrow[2 * WDIM + tid] = v0.z; vrow[3 * WDIM + tid] = v0.w;
        vrow[4 * WDIM + tid] = v1.x; vrow[5 * WDIM + tid] = v1.y;
        vrow[6 * WDIM + tid] = v1.z; vrow[7 * WDIM + tid] = v1.w;
    }
    __syncthreads();

    const float4* wr = (const float4*)(lin_w + (size_t)e * 2 * WDIM);
    float u0 = 0.f, u1 = 0.f, t0 = 0.f, t1 = 0.f;
#pragma unroll 8
    for (int q = 0; q < 32; ++q) {
        float4 w1 = wr[q];
        float4 w2 = wr[32 + q];
        float4 va = *(const float4*)&vrow[(ks * 2 + 0) * WDIM + q * 4];
        float4 vb = *(const float4*)&vrow[(ks * 2 + 1) * WDIM + q * 4];
        u0 += dot4(w1, va); u1 += dot4(w1, vb);
        t0 += dot4(w2, va); t1 += dot4(w2, vb);
    }
    const float lb = lin_b[e];
    const int k = k0 + ks * 2;
    const size_t o0 = ((size_t)b * KDIM + k) * EDIM + e;
    u_ws[o0] = u0;  u_ws[o0 + EDIM] = u1;

    t_lds[el][ks * 2 + 0] = t0 + lb;
    t_lds[el][ks * 2 + 1] = t1 + lb;
    __syncthreads();

    const int e_w = tid >> 2;
    const int c2  = (tid & 3) * 2;
    float2 tv = make_float2(t_lds[e_w][c2], t_lds[e_w][c2 + 1]);
    *(float2*)(tT_ws + ((size_t)b * EDIM + eq * 64 + e_w) * KDIM + k0 + c2) = tv;
}

// ---------------- k_fuse2: e + softmax + h, block = (b, i-pair) ----------------
// grid 512: blk = b*128 + ip; i0 = ip*2. 4 waves: wave wv = (ii = wv>>1, eh = wv&1).
// Phase 1: wave accumulates z over its 128-e half for row i0+ii; lane owns j = lane*4..+4
//          (tT rows read 1 KB/wave fully coalesced; u/a wave-uniform broadcasts).
// Phase 2: waves 0-1 combine 2 half-planes + ru + bias, softmax -> attn LDS.
// Phase 3: 4 waves x 32 w: h = sigmoid(attn @ v), float2 transposed store.
__global__ __launch_bounds__(256) void k_fuse2(const float* __restrict__ x,
                                               const float* __restrict__ a_vec,
                                               const float* __restrict__ bias,
                                               const float* __restrict__ u_ws,
                                               const float* __restrict__ tT_ws,
                                               float* __restrict__ out) {
    __shared__ float z_lds[4][256];
    __shared__ float ru_lds[4];
    __shared__ float attn_lds[2][260];
    const int blk = blockIdx.x;
    const int b  = blk >> 7;
    const int ip = blk & 127;
    const int i0 = ip * 2;
    const int tid  = threadIdx.x;
    const int wv   = tid >> 6;
    const int lane = tid & 63;

    // ---- phase 1 ----
    {
        const int ii = wv >> 1;
        const int eh = wv & 1;
        const int i  = i0 + ii;
        const int e0 = eh * 128;
        const float* urow  = u_ws + ((size_t)b * KDIM + i) * EDIM + e0;
        const float* arow  = a_vec + e0;
        const float* tbase = tT_ws + ((size_t)b * EDIM + e0) * KDIM + lane * 4;

        float4 acc = make_float4(0.f, 0.f, 0.f, 0.f);
        float4 rt  = make_float4(0.f, 0.f, 0.f, 0.f);
        float ru = 0.f;
#pragma unroll 4
        for (int e4 = 0; e4 < 32; ++e4) {
            float4 uv = *(const float4*)(urow + e4 * 4);   // wave-uniform
            float4 av = *(const float4*)(arow + e4 * 4);
            float uc[4] = {uv.x, uv.y, uv.z, uv.w};
            float ac[4] = {av.x, av.y, av.z, av.w};
#pragma unroll
            for (int r = 0; r < 4; ++r) {
                float4 t4 = *(const float4*)(tbase + (size_t)(e4 * 4 + r) * KDIM);
                const float c = 0.4f * ac[r];
                const float d = 0.6f * ac[r];
                acc.x += c * fabsf(uc[r] + t4.x);  rt.x += d * t4.x;
                acc.y += c * fabsf(uc[r] + t4.y);  rt.y += d * t4.y;
                acc.z += c * fabsf(uc[r] + t4.z);  rt.z += d * t4.z;
                acc.w += c * fabsf(uc[r] + t4.w);  rt.w += d * t4.w;
                ru += d * uc[r];
            }
        }
        float4 z;
        z.x = acc.x + rt.x; z.y = acc.y + rt.y;
        z.z = acc.z + rt.z; z.w = acc.w + rt.w;
        *(float4*)&z_lds[wv][lane * 4] = z;
        if (lane == 0) ru_lds[wv] = ru;
    }
    __syncthreads();

    // ---- phase 2: combine + softmax (waves 0-1; wave wv handles row i0+wv) ----
    if (wv < 2) {
        float4 z0 = *(const float4*)&z_lds[wv * 2 + 0][lane * 4];
        float4 z1 = *(const float4*)&z_lds[wv * 2 + 1][lane * 4];
        const float ru = ru_lds[wv * 2] + ru_lds[wv * 2 + 1];
        float4 bv = *(const float4*)(bias + (size_t)(i0 + wv) * KDIM + lane * 4);
        float4 ev;
        ev.x = z0.x + z1.x + ru + bv.x;
        ev.y = z0.y + z1.y + ru + bv.y;
        ev.z = z0.z + z1.z + ru + bv.z;
        ev.w = z0.w + z1.w + ru + bv.w;

        float m = fmaxf(fmaxf(ev.x, ev.y), fmaxf(ev.z, ev.w));
#pragma unroll
        for (int o = 1; o < 64; o <<= 1) m = fmaxf(m, __shfl_xor(m, o, 64));
        float4 p;
        p.x = __expf(ev.x - m); p.y = __expf(ev.y - m);
        p.z = __expf(ev.z - m); p.w = __expf(ev.w - m);
        float ssum = p.x + p.y + p.z + p.w;
#pragma unroll
        for (int o = 1; o < 64; o <<= 1) ssum += __shfl_xor(ssum, o, 64);
        const float inv = 1.0f / ssum;
        p.x *= inv; p.y *= inv; p.z *= inv; p.w *= inv;
        *(float4*)&attn_lds[wv][lane * 4] = p;
    }
    __syncthreads();

    // ---- phase 3: h = sigmoid(attn @ v); wave wv -> w in [wv*32, wv*32+32) ----
    const int s  = lane & 7;
    const int ww = lane >> 3;
#pragma unroll
    for (int c = 0; c < 4; ++c) {
        const int w = wv * 32 + c * 8 + ww;
        const float* xr = x + ((size_t)b * WDIM + w) * KDIM;
        float acc0 = 0.f, acc1 = 0.f;
#pragma unroll
        for (int q = 0; q < 8; ++q) {
            float4 x4 = *(const float4*)(xr + q * 32 + s * 4);
            float4 a0 = *(const float4*)&attn_lds[0][q * 32 + s * 4];
            float4 a1 = *(const float4*)&attn_lds[1][q * 32 + s * 4];
            acc0 += dot4(a0, x4);
            acc1 += dot4(a1, x4);
        }
        acc0 += __shfl_xor(acc0, 1, 64); acc1 += __shfl_xor(acc1, 1, 64);
        acc0 += __shfl_xor(acc0, 2, 64); acc1 += __shfl_xor(acc1, 2, 64);
        acc0 += __shfl_xor(acc0, 4, 64); acc1 += __shfl_xor(acc1, 4, 64);
        if (s == 0) {
            float2 o2;
            o2.x = 1.f / (1.f + __expf(-acc0));
            o2.y = 1.f / (1.f + __expf(-acc1));
            *(float2*)(out + ((size_t)b * WDIM + w) * KDIM + i0) = o2;
        }
    }
}

extern "C" void kernel_launch(void* const* d_in, const int* in_sizes, int n_in,
                              void* d_out, int out_size, void* d_ws, size_t ws_size,
                              hipStream_t stream) {
    (void)in_sizes; (void)n_in; (void)out_size; (void)ws_size;
    const float* x     = (const float*)d_in[0];
    const float* lin_w = (const float*)d_in[1];
    const float* lin_b = (const float*)d_in[2];
    const float* a_vec = (const float*)d_in[3];
    const float* bias  = (const float*)d_in[4];
    float* out = (float*)d_out;

    float* u_ws  = (float*)d_ws;                        // 262144 f
    float* tT_ws = u_ws + (size_t)NB * KDIM * EDIM;     // 262144 f

    k_ut10<<<512, 256, 0, stream>>>(x, lin_w, lin_b, u_ws, tT_ws);
    k_fuse2<<<512, 256, 0, stream>>>(x, a_vec, bias, u_ws, tT_ws, out);
}

// Round 11
// 41.478 us; speedup vs baseline: 1.0147x; 1.0147x over previous
//
#include <hip/hip_runtime.h>
#include <math.h>

#define NB 4
#define WDIM 128
#define KDIM 256
#define EDIM 256

__device__ __forceinline__ float dot4(float4 a, float4 b) {
    return a.x * b.x + a.y * b.y + a.z * b.z + a.w * b.w;
}

// XCD-pinned decomposition: xcd = blk&7 (HW round-robin), b = xcd>>1 — all blocks
// touching batch b run on XCDs {2b, 2b+1}; intermediates stay in that L2 pair.

// ---------------- k_ut11: dual GEMM u,t (r5-verified body) ----------------
// grid 512: wid = (blk>>3)*2 + (xcd&1) in [0,128): kt = wid>>2 (8 k's), eq = wid&3 (64 e's)
__global__ __launch_bounds__(256) void k_ut11(const float* __restrict__ x,
                                              const float* __restrict__ lin_w,
                                              const float* __restrict__ lin_b,
                                              float* __restrict__ u_ws,
                                              float* __restrict__ t_ws) {
    __shared__ float vrow[8 * WDIM];   // [k 8][w 128]
    const int blk = blockIdx.x;
    const int xcd = blk & 7;
    const int b   = xcd >> 1;
    const int wid = ((blk >> 3) << 1) | (xcd & 1);
    const int k0  = (wid >> 2) * 8;
    const int eq  = wid & 3;
    const int tid = threadIdx.x;
    const int e   = eq * 64 + (tid & 63);
    const int ks  = tid >> 6;

    if (tid < WDIM) {
        const float* xp = x + ((size_t)b * WDIM + tid) * KDIM + k0;
        float4 v0 = *(const float4*)xp;
        float4 v1 = *(const float4*)(xp + 4);
        vrow[0 * WDIM + tid] = v0.x; vrow[1 * WDIM + tid] = v0.y;
        vrow[2 * WDIM + tid] = v0.z; vrow[3 * WDIM + tid] = v0.w;
        vrow[4 * WDIM + tid] = v1.x; vrow[5 * WDIM + tid] = v1.y;
        vrow[6 * WDIM + tid] = v1.z; vrow[7 * WDIM + tid] = v1.w;
    }
    __syncthreads();

    const float4* wr = (const float4*)(lin_w + (size_t)e * 2 * WDIM);
    float u0 = 0.f, u1 = 0.f, t0 = 0.f, t1 = 0.f;
#pragma unroll 8
    for (int q = 0; q < 32; ++q) {
        float4 w1 = wr[q];
        float4 w2 = wr[32 + q];
        float4 va = *(const float4*)&vrow[(ks * 2 + 0) * WDIM + q * 4];
        float4 vb = *(const float4*)&vrow[(ks * 2 + 1) * WDIM + q * 4];
        u0 += dot4(w1, va); u1 += dot4(w1, vb);
        t0 += dot4(w2, va); t1 += dot4(w2, vb);
    }
    const float lb = lin_b[e];
    const int k = k0 + ks * 2;
    const size_t o0 = ((size_t)b * KDIM + k) * EDIM + e;
    u_ws[o0] = u0;         u_ws[o0 + EDIM] = u1;
    t_ws[o0] = t0 + lb;    t_ws[o0 + EDIM] = t1 + lb;
}

// ---------------- k_e11: e[b,i,j] = 0.4*sum a|u+t| + 0.6*(ru+rt) + bias ----------------
// grid 1024: wid in [0,256): it = wid>>3 (8 i's), jt = wid&7 (32 j's).
// wave owns 8 disjoint j's; lane = (s = lane&7 e-slice, jj = lane>>3). ZERO LDS.
__global__ __launch_bounds__(256) void k_e11(const float* __restrict__ a_vec,
                                             const float* __restrict__ bias,
                                             const float* __restrict__ u_ws,
                                             const float* __restrict__ t_ws,
                                             float* __restrict__ e_ws) {
    const int blk = blockIdx.x;
    const int xcd = blk & 7;
    const int b   = xcd >> 1;
    const int wid = ((blk >> 3) << 1) | (xcd & 1);
    const int i0  = (wid >> 3) * 8;
    const int jt  = wid & 7;
    const int tid  = threadIdx.x;
    const int wv   = tid >> 6;
    const int lane = tid & 63;
    const int s  = lane & 7;
    const int jj = lane >> 3;
    const int j  = jt * 32 + wv * 8 + jj;

    // t row slice in regs (8 lanes cover 128B of each of 8 rows per load)
    const float* trp = t_ws + ((size_t)b * KDIM + j) * EDIM;
    float4 tld[8];
#pragma unroll
    for (int q = 0; q < 8; ++q) tld[q] = *(const float4*)(trp + q * 32 + s * 4);

    float4 av[8];
#pragma unroll
    for (int q = 0; q < 8; ++q) av[q] = *(const float4*)(a_vec + q * 32 + s * 4);

    // rt = sum a*t, reduced over s now (all lanes end with full rt)
    float rt = 0.f;
#pragma unroll
    for (int q = 0; q < 8; ++q) rt += dot4(av[q], tld[q]);
    rt += __shfl_xor(rt, 1, 64);
    rt += __shfl_xor(rt, 2, 64);
    rt += __shfl_xor(rt, 4, 64);

#pragma unroll
    for (int p = 0; p < 2; ++p) {
        const int ib = i0 + p * 4;
        const float* up0 = u_ws + ((size_t)b * KDIM + ib) * EDIM;
        float acc[4] = {0.f, 0.f, 0.f, 0.f};
        float ru[4]  = {0.f, 0.f, 0.f, 0.f};
#pragma unroll
        for (int q = 0; q < 8; ++q) {
            const float4 aa = av[q];
            const float4 t4 = tld[q];
#pragma unroll
            for (int i = 0; i < 4; ++i) {
                float4 u4 = *(const float4*)(up0 + (size_t)i * EDIM + q * 32 + s * 4);
                ru[i]  += dot4(aa, u4);
                acc[i] += aa.x * fabsf(u4.x + t4.x) + aa.y * fabsf(u4.y + t4.y)
                        + aa.z * fabsf(u4.z + t4.z) + aa.w * fabsf(u4.w + t4.w);
            }
        }
#pragma unroll
        for (int i = 0; i < 4; ++i) {
            float z = 0.4f * acc[i] + 0.6f * ru[i];
            z += __shfl_xor(z, 1, 64);
            z += __shfl_xor(z, 2, 64);
            z += __shfl_xor(z, 4, 64);
            z += 0.6f * rt;
            if (s == 0) {
                e_ws[((size_t)b * KDIM + ib + i) * KDIM + j] =
                    z + bias[(size_t)(ib + i) * KDIM + j];
            }
        }
    }
}

// ---------------- k_sh11: softmax + h = sigmoid(attn @ v), transposed write ----------------
// grid 1024: wid in [0,256): it = wid>>2 (4 i's), wq = wid&3 (32 w's).
__global__ __launch_bounds__(256) void k_sh11(const float* __restrict__ x,
                                              const float* __restrict__ e_ws,
                                              float* __restrict__ out) {
    __shared__ float attn_lds[4][260];
    const int blk = blockIdx.x;
    const int xcd = blk & 7;
    const int b   = xcd >> 1;
    const int wid = ((blk >> 3) << 1) | (xcd & 1);
    const int i0  = (wid >> 2) * 4;
    const int w0  = (wid & 3) * 32;
    const int tid  = threadIdx.x;
    const int wv   = tid >> 6;
    const int lane = tid & 63;

    // softmax of row i0+wv (wave-parallel, contiguous 1 KB read)
    {
        float4 ev = *(const float4*)(e_ws + ((size_t)b * KDIM + i0 + wv) * KDIM + lane * 4);
        float m = fmaxf(fmaxf(ev.x, ev.y), fmaxf(ev.z, ev.w));
#pragma unroll
        for (int o = 1; o < 64; o <<= 1) m = fmaxf(m, __shfl_xor(m, o, 64));
        float4 p;
        p.x = __expf(ev.x - m); p.y = __expf(ev.y - m);
        p.z = __expf(ev.z - m); p.w = __expf(ev.w - m);
        float ssum = p.x + p.y + p.z + p.w;
#pragma unroll
        for (int o = 1; o < 64; o <<= 1) ssum += __shfl_xor(ssum, o, 64);
        const float inv = 1.0f / ssum;
        p.x *= inv; p.y *= inv; p.z *= inv; p.w *= inv;
        *(float4*)&attn_lds[wv][lane * 4] = p;
    }
    __syncthreads();

    // h-phase: wave wv -> w-oct; lane: s = lane&7 (j-slices), ww = lane>>3
    const int s  = lane & 7;
    const int ww = lane >> 3;
    const int w  = w0 + wv * 8 + ww;
    const float* xr = x + ((size_t)b * WDIM + w) * KDIM;
    float acc[4] = {0.f, 0.f, 0.f, 0.f};
#pragma unroll
    for (int q = 0; q < 8; ++q) {
        float4 x4 = *(const float4*)(xr + q * 32 + s * 4);
#pragma unroll
        for (int i = 0; i < 4; ++i) {
            float4 at = *(const float4*)&attn_lds[i][q * 32 + s * 4];
            acc[i] += dot4(at, x4);
        }
    }
#pragma unroll
    for (int i = 0; i < 4; ++i) {
        acc[i] += __shfl_xor(acc[i], 1, 64);
        acc[i] += __shfl_xor(acc[i], 2, 64);
        acc[i] += __shfl_xor(acc[i], 4, 64);
    }
    if (s == 0) {
        float4 o;
        o.x = 1.f / (1.f + __expf(-acc[0]));
        o.y = 1.f / (1.f + __expf(-acc[1]));
        o.z = 1.f / (1.f + __expf(-acc[2]));
        o.w = 1.f / (1.f + __expf(-acc[3]));
        *(float4*)(out + ((size_t)b * WDIM + w) * KDIM + i0) = o;
    }
}

extern "C" void kernel_launch(void* const* d_in, const int* in_sizes, int n_in,
                              void* d_out, int out_size, void* d_ws, size_t ws_size,
                              hipStream_t stream) {
    (void)in_sizes; (void)n_in; (void)out_size; (void)ws_size;
    const float* x     = (const float*)d_in[0];
    const float* lin_w = (const float*)d_in[1];
    const float* lin_b = (const float*)d_in[2];
    const float* a_vec = (const float*)d_in[3];
    const float* bias  = (const float*)d_in[4];
    float* out = (float*)d_out;

    float* u_ws = (float*)d_ws;                      // 262144 f
    float* t_ws = u_ws + (size_t)NB * KDIM * EDIM;   // 262144 f
    float* e_ws = t_ws + (size_t)NB * KDIM * EDIM;   // 262144 f

    k_ut11<<<512, 256, 0, stream>>>(x, lin_w, lin_b, u_ws, t_ws);
    k_e11<<<1024, 256, 0, stream>>>(a_vec, bias, u_ws, t_ws, e_ws);
    k_sh11<<<1024, 256, 0, stream>>>(x, e_ws, out);
}